// Round 10
// baseline (82.852 us; speedup 1.0000x reference)
//
#include <hip/hip_runtime.h>

// MoreParamDenseQConv1D — algebraic reduction, 2-kernel pipeline.
// out(r,oc) = w^T A_oc w / (w^T w), A_oc = Re(W[:,:32]^H diag(z0) W[:,:32]).
// With f_k = e_k^T A e_k and f_kl = (e_k+e_l)^T A (e_k+e_l):
//   w^T A w = sum_{k<l} f_kl w_k w_l + sum_k f_k w_k (2 w_k - S),  S = sum w.
// Pipeline:
//   1) prep_k : evolve 528 basis inputs per oc (32 singles, 496 pairs) with
//      the verified wave-level circuit machinery -> f values in ws.
//   2) quad_k : one thread per (2 rows, oc); 2x32 window floats in VGPRs;
//      row-factored pair sum; each wave-uniform F scalar load feeds 2 FMAs
//      (s_load amortization); divide by ||w||^2.

#define L_OUT 2041
#define N_ROWS (16 * L_OUT)   // 32656
#define NS 4

// ---------------- wave-level circuit machinery (verified R1-R7) -------------

__device__ __forceinline__ float bperm(int addr, float v) {
    return __int_as_float(__builtin_amdgcn_ds_bpermute(addr, __float_as_int(v)));
}

template <int CTRL>
__device__ __forceinline__ float fdpp(float v) {
    return __int_as_float(
        __builtin_amdgcn_mov_dpp(__float_as_int(v), CTRL, 0xf, 0xf, true));
}

// Full-wave sum; total lands in lane 63.
__device__ __forceinline__ float dpp_reduce(float v) {
    v += fdpp<0x111>(v);  // row_shr:1
    v += fdpp<0x112>(v);  // row_shr:2
    v += fdpp<0x114>(v);  // row_shr:4
    v += fdpp<0x118>(v);  // row_shr:8
    v += fdpp<0x142>(v);  // row_bcast:15
    v += fdpp<0x143>(v);  // row_bcast:31
    return v;
}

__device__ __forceinline__ void make_gates(const float* __restrict__ thetas,
                                           int oc, int lane, float* gc) {
    float o0, o1, o2, o3;
    {
        int g = lane < 14 ? lane : 0;
        int ti = (oc * 14 + g) * 3;
        float a = thetas[ti + 0], b = thetas[ti + 1], gm = thetas[ti + 2];
        float sb = sinf(b * 0.5f), cb = cosf(b * 0.5f);
        float sp, cp, sm, cm;
        sincosf((a + gm) * 0.5f, &sp, &cp);
        sincosf((a - gm) * 0.5f, &sm, &cm);
        o0 = cp * cb;
        o1 = -sp * cb;
        o2 = cm * sb;
        o3 = sm * sb;
    }
#pragma unroll
    for (int k = 0; k < 14; ++k) {
        gc[k * 4 + 0] = __int_as_float(__builtin_amdgcn_readlane(__float_as_int(o0), k));
        gc[k * 4 + 1] = __int_as_float(__builtin_amdgcn_readlane(__float_as_int(o1), k));
        gc[k * 4 + 2] = __int_as_float(__builtin_amdgcn_readlane(__float_as_int(o2), k));
        gc[k * 4 + 3] = __int_as_float(__builtin_amdgcn_readlane(__float_as_int(o3), k));
    }
}

// Evolve NS states through the full circuit (both layers + entangler diags).
__device__ __forceinline__ void evolve(float (&v0r)[NS], float (&v0i)[NS],
                                       float (&v1r)[NS], float (&v1i)[NS],
                                       const float (&gc)[56], int lane) {
#define GAPPLY(gi)                                                        \
    {                                                                     \
        float ur = gc[(gi)*4 + 0], ui = gc[(gi)*4 + 1];                   \
        float vr = gc[(gi)*4 + 2], vi = gc[(gi)*4 + 3];                   \
        _Pragma("unroll") for (int s = 0; s < NS; ++s) {                  \
            float n0r = ur * v0r[s] - ui * v0i[s] - vr * v1r[s] - vi * v1i[s]; \
            float n0i = ur * v0i[s] + ui * v0r[s] + vi * v1r[s] - vr * v1i[s]; \
            float n1r = vr * v0r[s] - vi * v0i[s] + ur * v1r[s] + ui * v1i[s]; \
            float n1i = vr * v0i[s] + vi * v0r[s] + ur * v1i[s] - ui * v1r[s]; \
            v0r[s] = n0r; v0i[s] = n0i; v1r[s] = n1r; v1i[s] = n1i;       \
        }                                                                 \
    }
#define RP32()                                                            \
    {                                                                     \
        _Pragma("unroll") for (int s = 0; s < NS; ++s) {                  \
            asm("v_permlane32_swap_b32 %0, %1" : "+v"(v0r[s]), "+v"(v1r[s])); \
            asm("v_permlane32_swap_b32 %0, %1" : "+v"(v0i[s]), "+v"(v1i[s])); \
        }                                                                 \
    }
#define RP16()                                                            \
    {                                                                     \
        _Pragma("unroll") for (int s = 0; s < NS; ++s) {                  \
            asm("v_permlane16_swap_b32 %0, %1" : "+v"(v0r[s]), "+v"(v1r[s])); \
            asm("v_permlane16_swap_b32 %0, %1" : "+v"(v0i[s]), "+v"(v1i[s])); \
        }                                                                 \
    }
#define RPB(m)                                                            \
    {                                                                     \
        bool hi = (lane & (m)) != 0;                                      \
        int ad = (lane ^ (m)) << 2;                                       \
        _Pragma("unroll") for (int s = 0; s < NS; ++s) {                  \
            float sr = hi ? v0r[s] : v1r[s];                              \
            float si = hi ? v0i[s] : v1i[s];                              \
            float rr = bperm(ad, sr);                                     \
            float ri = bperm(ad, si);                                     \
            v0r[s] = hi ? rr : v0r[s];                                    \
            v0i[s] = hi ? ri : v0i[s];                                    \
            v1r[s] = hi ? v1r[s] : rr;                                    \
            v1i[s] = hi ? v1i[s] : ri;                                    \
        }                                                                 \
    }
#define RPD(m, CTRL)                                                      \
    {                                                                     \
        bool hi = (lane & (m)) != 0;                                      \
        _Pragma("unroll") for (int s = 0; s < NS; ++s) {                  \
            float t0r = fdpp<CTRL>(v0r[s]), t0i = fdpp<CTRL>(v0i[s]);     \
            float t1r = fdpp<CTRL>(v1r[s]), t1i = fdpp<CTRL>(v1i[s]);     \
            v0r[s] = hi ? t1r : v0r[s];                                   \
            v0i[s] = hi ? t1i : v0i[s];                                   \
            v1r[s] = hi ? v1r[s] : t0r;                                   \
            v1i[s] = hi ? v1i[s] : t0i;                                   \
        }                                                                 \
    }
    {
        float ur = gc[0], ui = gc[1], vr = gc[2], vi = gc[3];
#pragma unroll
        for (int s = 0; s < NS; ++s) {
            float xx = v0r[s];
            v0r[s] = ur * xx; v0i[s] = ui * xx;
            v1r[s] = vr * xx; v1i[s] = vi * xx;
        }
    }
    RP32();
    {
        float ur = gc[4], ui = gc[5], vr = gc[6], vi = gc[7];
#pragma unroll
        for (int s = 0; s < NS; ++s) {
            float x0r = v0r[s], x0i = v0i[s];
            v0r[s] = ur * x0r - ui * x0i; v0i[s] = ur * x0i + ui * x0r;
            v1r[s] = vr * x0r - vi * x0i; v1i[s] = vr * x0i + vi * x0r;
        }
    }
    RP16();       GAPPLY(2);
    RPB(8);       GAPPLY(3);
    RPB(4);       GAPPLY(4);
    RPD(2, 0x4E); GAPPLY(5);
    RPD(1, 0xB1); GAPPLY(6);

    int kc = __popc(lane);
    float s0 = ((kc >> 1) & 1) ? -1.f : 1.f;
    float s1 = (((kc + 1) >> 1) & 1) ? -1.f : 1.f;
#pragma unroll
    for (int s = 0; s < NS; ++s) {
        v0r[s] *= s0; v0i[s] *= s0; v1r[s] *= s1; v1i[s] *= s1;
    }

    RP32();       GAPPLY(7);
    RP16();       GAPPLY(8);
    RPB(8);       GAPPLY(9);
    RPB(4);       GAPPLY(10);
    RPD(2, 0x4E); GAPPLY(11);
    RPD(1, 0xB1); GAPPLY(12);
    RP32();       GAPPLY(13);
#pragma unroll
    for (int s = 0; s < NS; ++s) {
        v0r[s] *= s0; v0i[s] *= s0; v1r[s] *= s1; v1i[s] *= s1;
    }
#undef GAPPLY
#undef RP32
#undef RP16
#undef RPB
#undef RPD
}

__device__ __forceinline__ void measure(float (&v0r)[NS], float (&v0i)[NS],
                                        float (&v1r)[NS], float (&v1i)[NS],
                                        int lane, float (&e)[NS]) {
#pragma unroll
    for (int s = 0; s < NS; ++s) {
        float t = v0r[s] * v0r[s] + v0i[s] * v0i[s] + v1r[s] * v1r[s] + v1i[s] * v1i[s];
        e[s] = (lane & 16) ? -t : t;
        e[s] = dpp_reduce(e[s]);
    }
}

// pair offset: off(k) = 31k - k(k-1)/2 (row k holds l=k+1..31)
__device__ __forceinline__ int pair_off(int k) { return 31 * k - (k * (k - 1)) / 2; }

// ---------------- kernel 1: basis evolutions -> f values --------------------
// fbuf layout per oc (stride 544): [0..31] singles f_k ; [32+off(k)+l-k-1] pairs.
__global__ __launch_bounds__(512) void prep_k(const float* __restrict__ thetas,
                                              float* __restrict__ fbuf) {
    int lane = threadIdx.x & 63;
    int iw = threadIdx.x >> 6;
    int oc = __builtin_amdgcn_readfirstlane(blockIdx.x / 17);
    int chunk = blockIdx.x % 17;

    float gc[56];
    make_gates(thetas, oc, lane, gc);

    float v0r[NS], v0i[NS], v1r[NS], v1i[NS];
    int idxs[NS];
#pragma unroll
    for (int s = 0; s < NS; ++s) {
        int idx = chunk * 32 + iw * 4 + s;
        if (idx > 527) idx = 527;
        idxs[s] = idx;
        int k, l;
        if (idx < 32) {
            k = idx; l = idx;
        } else {
            int p = idx - 32;
            k = (int)((63.0f - sqrtf(3969.0f - 8.0f * (float)p)) * 0.5f);
            if (k > 0 && pair_off(k) > p) --k;
            if (pair_off(k + 1) <= p) ++k;
            l = k + 1 + (p - pair_off(k));
        }
        v0r[s] = (lane == k || lane == l) ? 1.f : 0.f;
        v0i[s] = 0.f; v1r[s] = 0.f; v1i[s] = 0.f;
    }

    evolve(v0r, v0i, v1r, v1i, gc, lane);
    float e[NS];
    measure(v0r, v0i, v1r, v1i, lane, e);
    if (lane == 63) {
#pragma unroll
        for (int s = 0; s < NS; ++s) fbuf[oc * 544 + idxs[s]] = e[s];
    }
}

// ---------------- kernel 2: quadratic form, 2 rows per thread ---------------
// out*n2 = sum_k w_k * [ sum_{l>k} f_kl w_l + f_k*(2 w_k - S) ]
// Each F scalar load feeds both rows' FMAs (s_load amortization).
__global__ __launch_bounds__(512) void quad_k(const float* __restrict__ x,
                                              const float* __restrict__ F,
                                              float* __restrict__ out) {
    int lane = threadIdx.x & 63;
    int oc = __builtin_amdgcn_readfirstlane((int)(threadIdx.x >> 6));

    int rowA = blockIdx.x * 128 + lane;
    int rowB = rowA + 64;
    bool vA = rowA < N_ROWS, vB = rowB < N_ROWS;
    int rA = vA ? rowA : (N_ROWS - 1);
    int rB = vB ? rowB : (N_ROWS - 1);
    int bA = rA / L_OUT, lA = rA - bA * L_OUT;
    int bB = rB / L_OUT, lB = rB - bB * L_OUT;

    const float* xa = x + (bA * 4) * 2048 + lA;
    const float* xb = x + (bB * 4) * 2048 + lB;
    float w0[32], w1[32];
#pragma unroll
    for (int c = 0; c < 4; ++c)
#pragma unroll
        for (int k = 0; k < 8; ++k) {
            w0[c * 8 + k] = xa[c * 2048 + k];
            w1[c * 8 + k] = xb[c * 2048 + k];
        }

    float n2a = 0.f, Sa = 0.f, n2b = 0.f, Sb = 0.f;
#pragma unroll
    for (int i = 0; i < 32; ++i) {
        n2a = fmaf(w0[i], w0[i], n2a); Sa += w0[i];
        n2b = fmaf(w1[i], w1[i], n2b); Sb += w1[i];
    }

    const float* fo = F + oc * 544;  // wave-uniform -> scalar loads
    float a0 = 0.f, a1 = 0.f, b0 = 0.f, b1 = 0.f;
#pragma unroll
    for (int k = 0; k < 32; ++k) {
        const float* fr = fo + 32 + (31 * k - (k * (k - 1)) / 2) - k - 1;
        float tA0 = 0.f, tA1 = 0.f, tB0 = 0.f, tB1 = 0.f;
#pragma unroll
        for (int j = k + 1; j < 32; j += 2) {
            float fv = fr[j];
            tA0 = fmaf(fv, w0[j], tA0);
            tB0 = fmaf(fv, w1[j], tB0);
        }
#pragma unroll
        for (int j = k + 2; j < 32; j += 2) {
            float fv = fr[j];
            tA1 = fmaf(fv, w0[j], tA1);
            tB1 = fmaf(fv, w1[j], tB1);
        }
        float fk = fo[k];
        float tA = fmaf(fk, fmaf(2.f, w0[k], -Sa), tA0 + tA1);
        float tB = fmaf(fk, fmaf(2.f, w1[k], -Sb), tB0 + tB1);
        if (k & 1) { a1 = fmaf(w0[k], tA, a1); b1 = fmaf(w1[k], tB, b1); }
        else       { a0 = fmaf(w0[k], tA, a0); b0 = fmaf(w1[k], tB, b0); }
    }
    if (vA)
        out[(bA * 8 + oc) * L_OUT + lA] = (a0 + a1) * __builtin_amdgcn_rcpf(n2a);
    if (vB)
        out[(bB * 8 + oc) * L_OUT + lB] = (b0 + b1) * __builtin_amdgcn_rcpf(n2b);
}

// ---------------- fallback: direct evolution (R4-style) ---------------------
__global__ __launch_bounds__(512) void direct_k(const float* __restrict__ x,
                                                const float* __restrict__ thetas,
                                                float* __restrict__ out) {
    int lane = threadIdx.x & 63;
    int oc = __builtin_amdgcn_readfirstlane((int)(threadIdx.x >> 6));
    float gc[56];
    make_gates(thetas, oc, lane, gc);

    int row0 = blockIdx.x * NS;
    int bidx[NS], lidx[NS];
    float v0r[NS], v0i[NS], v1r[NS], v1i[NS], acc[NS];
#pragma unroll
    for (int s = 0; s < NS; ++s) {
        int row = row0 + s;
        int b = row / L_OUT;
        bidx[s] = b;
        lidx[s] = row - b * L_OUT;
        float t = 0.f;
        if (lane < 32) {
            int c = lane >> 3, k = lane & 7;
            t = x[(b * 4 + c) * 2048 + lidx[s] + k];
        }
        acc[s] = t * t;
        v0r[s] = t; v0i[s] = 0.f; v1r[s] = 0.f; v1i[s] = 0.f;
    }
    evolve(v0r, v0i, v1r, v1i, gc, lane);
    float e[NS];
    measure(v0r, v0i, v1r, v1i, lane, e);
#pragma unroll
    for (int s = 0; s < NS; ++s) acc[s] = dpp_reduce(acc[s]);
    if (lane == 63) {
#pragma unroll
        for (int s = 0; s < NS; ++s)
            out[(bidx[s] * 8 + oc) * L_OUT + lidx[s]] =
                e[s] * __builtin_amdgcn_rcpf(acc[s]);
    }
}

extern "C" void kernel_launch(void* const* d_in, const int* in_sizes, int n_in,
                              void* d_out, int out_size, void* d_ws, size_t ws_size,
                              hipStream_t stream) {
    const float* x = (const float*)d_in[0];
    const float* thetas = (const float*)d_in[1];
    float* out = (float*)d_out;

    if (ws_size >= (8 * 544) * sizeof(float)) {
        float* fbuf = (float*)d_ws;
        prep_k<<<136, 512, 0, stream>>>(thetas, fbuf);
        quad_k<<<(N_ROWS + 127) / 128, 512, 0, stream>>>(x, fbuf, out);
    } else {
        direct_k<<<N_ROWS / NS, 512, 0, stream>>>(x, thetas, out);
    }
}

// Round 11
// 69.933 us; speedup vs baseline: 1.1847x; 1.1847x over previous
//
#include <hip/hip_runtime.h>

// MoreParamDenseQConv1D — algebraic reduction, 2-kernel pipeline.
// out(r,oc) = w^T A_oc w / (w^T w), A_oc = Re(W[:,:32]^H diag(z0) W[:,:32]).
// With f_k = e_k^T A e_k and f_kl = (e_k+e_l)^T A (e_k+e_l):
//   w^T A w = sum_{k<l} f_kl w_k w_l + sum_k f_k w_k (2 w_k - S),  S = sum w.
// Pipeline:
//   1) prep_k : evolve 528 basis inputs per oc (32 singles, 496 pairs) with
//      the verified wave-level circuit machinery -> f values in ws.
//   2) quad_k : 1024-thread blocks = 16 waves; waves 0-7 handle oc 0-7 with
//      balanced k-set {0..7,24..31}, waves 8-15 the same 64 rows with k-set
//      {8..23} (248 pair-terms each). Wave-uniform split (no divergence);
//      per-wave serial chain and scalar-F footprint halve; 2 KB LDS combine.
//      R10 lesson: quad is latency/occupancy-bound -> more waves, shorter
//      chains (R10's 2-rows/thread cut waves 2x and regressed +10 us).

#define L_OUT 2041
#define N_ROWS (16 * L_OUT)   // 32656
#define NS 4

// ---------------- wave-level circuit machinery (verified R1-R7) -------------

__device__ __forceinline__ float bperm(int addr, float v) {
    return __int_as_float(__builtin_amdgcn_ds_bpermute(addr, __float_as_int(v)));
}

template <int CTRL>
__device__ __forceinline__ float fdpp(float v) {
    return __int_as_float(
        __builtin_amdgcn_mov_dpp(__float_as_int(v), CTRL, 0xf, 0xf, true));
}

// Full-wave sum; total lands in lane 63.
__device__ __forceinline__ float dpp_reduce(float v) {
    v += fdpp<0x111>(v);  // row_shr:1
    v += fdpp<0x112>(v);  // row_shr:2
    v += fdpp<0x114>(v);  // row_shr:4
    v += fdpp<0x118>(v);  // row_shr:8
    v += fdpp<0x142>(v);  // row_bcast:15
    v += fdpp<0x143>(v);  // row_bcast:31
    return v;
}

__device__ __forceinline__ void make_gates(const float* __restrict__ thetas,
                                           int oc, int lane, float* gc) {
    float o0, o1, o2, o3;
    {
        int g = lane < 14 ? lane : 0;
        int ti = (oc * 14 + g) * 3;
        float a = thetas[ti + 0], b = thetas[ti + 1], gm = thetas[ti + 2];
        float sb = sinf(b * 0.5f), cb = cosf(b * 0.5f);
        float sp, cp, sm, cm;
        sincosf((a + gm) * 0.5f, &sp, &cp);
        sincosf((a - gm) * 0.5f, &sm, &cm);
        o0 = cp * cb;
        o1 = -sp * cb;
        o2 = cm * sb;
        o3 = sm * sb;
    }
#pragma unroll
    for (int k = 0; k < 14; ++k) {
        gc[k * 4 + 0] = __int_as_float(__builtin_amdgcn_readlane(__float_as_int(o0), k));
        gc[k * 4 + 1] = __int_as_float(__builtin_amdgcn_readlane(__float_as_int(o1), k));
        gc[k * 4 + 2] = __int_as_float(__builtin_amdgcn_readlane(__float_as_int(o2), k));
        gc[k * 4 + 3] = __int_as_float(__builtin_amdgcn_readlane(__float_as_int(o3), k));
    }
}

// Evolve NS states through the full circuit (both layers + entangler diags).
__device__ __forceinline__ void evolve(float (&v0r)[NS], float (&v0i)[NS],
                                       float (&v1r)[NS], float (&v1i)[NS],
                                       const float (&gc)[56], int lane) {
#define GAPPLY(gi)                                                        \
    {                                                                     \
        float ur = gc[(gi)*4 + 0], ui = gc[(gi)*4 + 1];                   \
        float vr = gc[(gi)*4 + 2], vi = gc[(gi)*4 + 3];                   \
        _Pragma("unroll") for (int s = 0; s < NS; ++s) {                  \
            float n0r = ur * v0r[s] - ui * v0i[s] - vr * v1r[s] - vi * v1i[s]; \
            float n0i = ur * v0i[s] + ui * v0r[s] + vi * v1r[s] - vr * v1i[s]; \
            float n1r = vr * v0r[s] - vi * v0i[s] + ur * v1r[s] + ui * v1i[s]; \
            float n1i = vr * v0i[s] + vi * v0r[s] + ur * v1i[s] - ui * v1r[s]; \
            v0r[s] = n0r; v0i[s] = n0i; v1r[s] = n1r; v1i[s] = n1i;       \
        }                                                                 \
    }
#define RP32()                                                            \
    {                                                                     \
        _Pragma("unroll") for (int s = 0; s < NS; ++s) {                  \
            asm("v_permlane32_swap_b32 %0, %1" : "+v"(v0r[s]), "+v"(v1r[s])); \
            asm("v_permlane32_swap_b32 %0, %1" : "+v"(v0i[s]), "+v"(v1i[s])); \
        }                                                                 \
    }
#define RP16()                                                            \
    {                                                                     \
        _Pragma("unroll") for (int s = 0; s < NS; ++s) {                  \
            asm("v_permlane16_swap_b32 %0, %1" : "+v"(v0r[s]), "+v"(v1r[s])); \
            asm("v_permlane16_swap_b32 %0, %1" : "+v"(v0i[s]), "+v"(v1i[s])); \
        }                                                                 \
    }
#define RPB(m)                                                            \
    {                                                                     \
        bool hi = (lane & (m)) != 0;                                      \
        int ad = (lane ^ (m)) << 2;                                       \
        _Pragma("unroll") for (int s = 0; s < NS; ++s) {                  \
            float sr = hi ? v0r[s] : v1r[s];                              \
            float si = hi ? v0i[s] : v1i[s];                              \
            float rr = bperm(ad, sr);                                     \
            float ri = bperm(ad, si);                                     \
            v0r[s] = hi ? rr : v0r[s];                                    \
            v0i[s] = hi ? ri : v0i[s];                                    \
            v1r[s] = hi ? v1r[s] : rr;                                    \
            v1i[s] = hi ? v1i[s] : ri;                                    \
        }                                                                 \
    }
#define RPD(m, CTRL)                                                      \
    {                                                                     \
        bool hi = (lane & (m)) != 0;                                      \
        _Pragma("unroll") for (int s = 0; s < NS; ++s) {                  \
            float t0r = fdpp<CTRL>(v0r[s]), t0i = fdpp<CTRL>(v0i[s]);     \
            float t1r = fdpp<CTRL>(v1r[s]), t1i = fdpp<CTRL>(v1i[s]);     \
            v0r[s] = hi ? t1r : v0r[s];                                   \
            v0i[s] = hi ? t1i : v0i[s];                                   \
            v1r[s] = hi ? v1r[s] : t0r;                                   \
            v1i[s] = hi ? v1i[s] : t0i;                                   \
        }                                                                 \
    }
    {
        float ur = gc[0], ui = gc[1], vr = gc[2], vi = gc[3];
#pragma unroll
        for (int s = 0; s < NS; ++s) {
            float xx = v0r[s];
            v0r[s] = ur * xx; v0i[s] = ui * xx;
            v1r[s] = vr * xx; v1i[s] = vi * xx;
        }
    }
    RP32();
    {
        float ur = gc[4], ui = gc[5], vr = gc[6], vi = gc[7];
#pragma unroll
        for (int s = 0; s < NS; ++s) {
            float x0r = v0r[s], x0i = v0i[s];
            v0r[s] = ur * x0r - ui * x0i; v0i[s] = ur * x0i + ui * x0r;
            v1r[s] = vr * x0r - vi * x0i; v1i[s] = vr * x0i + vi * x0r;
        }
    }
    RP16();       GAPPLY(2);
    RPB(8);       GAPPLY(3);
    RPB(4);       GAPPLY(4);
    RPD(2, 0x4E); GAPPLY(5);
    RPD(1, 0xB1); GAPPLY(6);

    int kc = __popc(lane);
    float s0 = ((kc >> 1) & 1) ? -1.f : 1.f;
    float s1 = (((kc + 1) >> 1) & 1) ? -1.f : 1.f;
#pragma unroll
    for (int s = 0; s < NS; ++s) {
        v0r[s] *= s0; v0i[s] *= s0; v1r[s] *= s1; v1i[s] *= s1;
    }

    RP32();       GAPPLY(7);
    RP16();       GAPPLY(8);
    RPB(8);       GAPPLY(9);
    RPB(4);       GAPPLY(10);
    RPD(2, 0x4E); GAPPLY(11);
    RPD(1, 0xB1); GAPPLY(12);
    RP32();       GAPPLY(13);
#pragma unroll
    for (int s = 0; s < NS; ++s) {
        v0r[s] *= s0; v0i[s] *= s0; v1r[s] *= s1; v1i[s] *= s1;
    }
#undef GAPPLY
#undef RP32
#undef RP16
#undef RPB
#undef RPD
}

__device__ __forceinline__ void measure(float (&v0r)[NS], float (&v0i)[NS],
                                        float (&v1r)[NS], float (&v1i)[NS],
                                        int lane, float (&e)[NS]) {
#pragma unroll
    for (int s = 0; s < NS; ++s) {
        float t = v0r[s] * v0r[s] + v0i[s] * v0i[s] + v1r[s] * v1r[s] + v1i[s] * v1i[s];
        e[s] = (lane & 16) ? -t : t;
        e[s] = dpp_reduce(e[s]);
    }
}

// pair offset: off(k) = 31k - k(k-1)/2 (row k holds l=k+1..31)
__device__ __forceinline__ int pair_off(int k) { return 31 * k - (k * (k - 1)) / 2; }

// ---------------- kernel 1: basis evolutions -> f values --------------------
// fbuf layout per oc (stride 544): [0..31] singles f_k ; [32+off(k)+l-k-1] pairs.
__global__ __launch_bounds__(512) void prep_k(const float* __restrict__ thetas,
                                              float* __restrict__ fbuf) {
    int lane = threadIdx.x & 63;
    int iw = threadIdx.x >> 6;
    int oc = __builtin_amdgcn_readfirstlane(blockIdx.x / 17);
    int chunk = blockIdx.x % 17;

    float gc[56];
    make_gates(thetas, oc, lane, gc);

    float v0r[NS], v0i[NS], v1r[NS], v1i[NS];
    int idxs[NS];
#pragma unroll
    for (int s = 0; s < NS; ++s) {
        int idx = chunk * 32 + iw * 4 + s;
        if (idx > 527) idx = 527;
        idxs[s] = idx;
        int k, l;
        if (idx < 32) {
            k = idx; l = idx;
        } else {
            int p = idx - 32;
            k = (int)((63.0f - sqrtf(3969.0f - 8.0f * (float)p)) * 0.5f);
            if (k > 0 && pair_off(k) > p) --k;
            if (pair_off(k + 1) <= p) ++k;
            l = k + 1 + (p - pair_off(k));
        }
        v0r[s] = (lane == k || lane == l) ? 1.f : 0.f;
        v0i[s] = 0.f; v1r[s] = 0.f; v1i[s] = 0.f;
    }

    evolve(v0r, v0i, v1r, v1i, gc, lane);
    float e[NS];
    measure(v0r, v0i, v1r, v1i, lane, e);
    if (lane == 63) {
#pragma unroll
        for (int s = 0; s < NS; ++s) fbuf[oc * 544 + idxs[s]] = e[s];
    }
}

// per-k contribution: w_k * [ sum_{l>k} f_kl w_l + f_k (2 w_k - S) ]
// K compile-time -> all F offsets are s_load immediates.
template <int K>
__device__ __forceinline__ void kterm(const float* __restrict__ fo,
                                      const float (&w)[32], float S,
                                      float& a0, float& a1) {
    const float* fr = fo + 32 + (31 * K - (K * (K - 1)) / 2) - K - 1;
    float t0 = 0.f, t1 = 0.f;
#pragma unroll
    for (int j = K + 1; j < 32; j += 2) t0 = fmaf(fr[j], w[j], t0);
#pragma unroll
    for (int j = K + 2; j < 32; j += 2) t1 = fmaf(fr[j], w[j], t1);
    float t = fmaf(fo[K], fmaf(2.f, w[K], -S), t0 + t1);
    if (K & 1) a1 = fmaf(w[K], t, a1);
    else       a0 = fmaf(w[K], t, a0);
}

// ---------------- kernel 2: quadratic form, split-k wave pairs --------------
// 16 waves/block: wid&7 = oc, wid>>3 = half. Both halves: same 64 rows.
// half 0: k in {0..7, 24..31} (248 pair terms); half 1: k in {8..23} (248).
__global__ __launch_bounds__(1024, 8) void quad_k(const float* __restrict__ x,
                                                  const float* __restrict__ F,
                                                  float* __restrict__ out) {
    int lane = threadIdx.x & 63;
    int wid = threadIdx.x >> 6;
    int oc = __builtin_amdgcn_readfirstlane(wid & 7);
    int half = __builtin_amdgcn_readfirstlane(wid >> 3);

    int row = blockIdx.x * 64 + lane;
    bool valid = row < N_ROWS;
    int rc = valid ? row : (N_ROWS - 1);
    int b = rc / L_OUT;
    int l = rc - b * L_OUT;

    const float* xb = x + (b * 4) * 2048 + l;
    float w[32];
#pragma unroll
    for (int c = 0; c < 4; ++c)
#pragma unroll
        for (int k = 0; k < 8; ++k) w[c * 8 + k] = xb[c * 2048 + k];

    float n2 = 0.f, S = 0.f;
#pragma unroll
    for (int i = 0; i < 32; ++i) {
        n2 = fmaf(w[i], w[i], n2);
        S += w[i];
    }

    const float* fo = F + oc * 544;  // wave-uniform -> scalar loads
    float a0 = 0.f, a1 = 0.f;
    __shared__ float part[8][64];

    if (half) {
        kterm<8>(fo, w, S, a0, a1);  kterm<9>(fo, w, S, a0, a1);
        kterm<10>(fo, w, S, a0, a1); kterm<11>(fo, w, S, a0, a1);
        kterm<12>(fo, w, S, a0, a1); kterm<13>(fo, w, S, a0, a1);
        kterm<14>(fo, w, S, a0, a1); kterm<15>(fo, w, S, a0, a1);
        kterm<16>(fo, w, S, a0, a1); kterm<17>(fo, w, S, a0, a1);
        kterm<18>(fo, w, S, a0, a1); kterm<19>(fo, w, S, a0, a1);
        kterm<20>(fo, w, S, a0, a1); kterm<21>(fo, w, S, a0, a1);
        kterm<22>(fo, w, S, a0, a1); kterm<23>(fo, w, S, a0, a1);
        part[oc][lane] = a0 + a1;
    } else {
        kterm<0>(fo, w, S, a0, a1);  kterm<1>(fo, w, S, a0, a1);
        kterm<2>(fo, w, S, a0, a1);  kterm<3>(fo, w, S, a0, a1);
        kterm<4>(fo, w, S, a0, a1);  kterm<5>(fo, w, S, a0, a1);
        kterm<6>(fo, w, S, a0, a1);  kterm<7>(fo, w, S, a0, a1);
        kterm<24>(fo, w, S, a0, a1); kterm<25>(fo, w, S, a0, a1);
        kterm<26>(fo, w, S, a0, a1); kterm<27>(fo, w, S, a0, a1);
        kterm<28>(fo, w, S, a0, a1); kterm<29>(fo, w, S, a0, a1);
        kterm<30>(fo, w, S, a0, a1); kterm<31>(fo, w, S, a0, a1);
    }
    __syncthreads();
    if (!half && valid) {
        float tot = a0 + a1 + part[oc][lane];
        out[(b * 8 + oc) * L_OUT + l] = tot * __builtin_amdgcn_rcpf(n2);
    }
}

// ---------------- fallback: direct evolution (R4-style) ---------------------
__global__ __launch_bounds__(512) void direct_k(const float* __restrict__ x,
                                                const float* __restrict__ thetas,
                                                float* __restrict__ out) {
    int lane = threadIdx.x & 63;
    int oc = __builtin_amdgcn_readfirstlane((int)(threadIdx.x >> 6));
    float gc[56];
    make_gates(thetas, oc, lane, gc);

    int row0 = blockIdx.x * NS;
    int bidx[NS], lidx[NS];
    float v0r[NS], v0i[NS], v1r[NS], v1i[NS], acc[NS];
#pragma unroll
    for (int s = 0; s < NS; ++s) {
        int row = row0 + s;
        int b = row / L_OUT;
        bidx[s] = b;
        lidx[s] = row - b * L_OUT;
        float t = 0.f;
        if (lane < 32) {
            int c = lane >> 3, k = lane & 7;
            t = x[(b * 4 + c) * 2048 + lidx[s] + k];
        }
        acc[s] = t * t;
        v0r[s] = t; v0i[s] = 0.f; v1r[s] = 0.f; v1i[s] = 0.f;
    }
    evolve(v0r, v0i, v1r, v1i, gc, lane);
    float e[NS];
    measure(v0r, v0i, v1r, v1i, lane, e);
#pragma unroll
    for (int s = 0; s < NS; ++s) acc[s] = dpp_reduce(acc[s]);
    if (lane == 63) {
#pragma unroll
        for (int s = 0; s < NS; ++s)
            out[(bidx[s] * 8 + oc) * L_OUT + lidx[s]] =
                e[s] * __builtin_amdgcn_rcpf(acc[s]);
    }
}

extern "C" void kernel_launch(void* const* d_in, const int* in_sizes, int n_in,
                              void* d_out, int out_size, void* d_ws, size_t ws_size,
                              hipStream_t stream) {
    const float* x = (const float*)d_in[0];
    const float* thetas = (const float*)d_in[1];
    float* out = (float*)d_out;

    if (ws_size >= (8 * 544) * sizeof(float)) {
        float* fbuf = (float*)d_ws;
        prep_k<<<136, 512, 0, stream>>>(thetas, fbuf);
        quad_k<<<(N_ROWS + 63) / 64, 1024, 0, stream>>>(x, fbuf, out);
    } else {
        direct_k<<<N_ROWS / NS, 512, 0, stream>>>(x, thetas, out);
    }
}

// Round 13
// 69.853 us; speedup vs baseline: 1.1861x; 1.0012x over previous
//
#include <hip/hip_runtime.h>

// MoreParamDenseQConv1D — algebraic reduction, 2-kernel pipeline.
// out(r,oc) = w^T A_oc w / (w^T w), A_oc = Re(W[:,:32]^H diag(z0) W[:,:32]).
// With f_k = e_k^T A e_k and f_kl = (e_k+e_l)^T A (e_k+e_l):
//   w^T A w = sum_{k<l} f_kl w_k w_l + sum_k f_k w_k (2 w_k - S),  S = sum w.
// Pipeline:
//   1) prep_k : evolve 528 basis inputs per oc (32 singles, 496 pairs) with
//      the verified wave-level circuit machinery -> f values in ws.
//   2) quad_k : 1024-thread blocks = 16 waves; waves 0-7 handle oc 0-7 with
//      balanced k-set {0..7,24..31}, waves 8-15 the same 64 rows with k-set
//      {8..23} (248 pair-terms each). Wave-uniform split (no divergence);
//      per-wave serial chain and scalar-F footprint halve; 2 KB LDS combine.
// R12 lesson: prep NS=1 template restructure broke correctness — reverted to
// this exact R11-verified source (69.9 us).

#define L_OUT 2041
#define N_ROWS (16 * L_OUT)   // 32656
#define NS 4

// ---------------- wave-level circuit machinery (verified R1-R11) ------------

__device__ __forceinline__ float bperm(int addr, float v) {
    return __int_as_float(__builtin_amdgcn_ds_bpermute(addr, __float_as_int(v)));
}

template <int CTRL>
__device__ __forceinline__ float fdpp(float v) {
    return __int_as_float(
        __builtin_amdgcn_mov_dpp(__float_as_int(v), CTRL, 0xf, 0xf, true));
}

// Full-wave sum; total lands in lane 63.
__device__ __forceinline__ float dpp_reduce(float v) {
    v += fdpp<0x111>(v);  // row_shr:1
    v += fdpp<0x112>(v);  // row_shr:2
    v += fdpp<0x114>(v);  // row_shr:4
    v += fdpp<0x118>(v);  // row_shr:8
    v += fdpp<0x142>(v);  // row_bcast:15
    v += fdpp<0x143>(v);  // row_bcast:31
    return v;
}

__device__ __forceinline__ void make_gates(const float* __restrict__ thetas,
                                           int oc, int lane, float* gc) {
    float o0, o1, o2, o3;
    {
        int g = lane < 14 ? lane : 0;
        int ti = (oc * 14 + g) * 3;
        float a = thetas[ti + 0], b = thetas[ti + 1], gm = thetas[ti + 2];
        float sb = sinf(b * 0.5f), cb = cosf(b * 0.5f);
        float sp, cp, sm, cm;
        sincosf((a + gm) * 0.5f, &sp, &cp);
        sincosf((a - gm) * 0.5f, &sm, &cm);
        o0 = cp * cb;
        o1 = -sp * cb;
        o2 = cm * sb;
        o3 = sm * sb;
    }
#pragma unroll
    for (int k = 0; k < 14; ++k) {
        gc[k * 4 + 0] = __int_as_float(__builtin_amdgcn_readlane(__float_as_int(o0), k));
        gc[k * 4 + 1] = __int_as_float(__builtin_amdgcn_readlane(__float_as_int(o1), k));
        gc[k * 4 + 2] = __int_as_float(__builtin_amdgcn_readlane(__float_as_int(o2), k));
        gc[k * 4 + 3] = __int_as_float(__builtin_amdgcn_readlane(__float_as_int(o3), k));
    }
}

// Evolve NS states through the full circuit (both layers + entangler diags).
__device__ __forceinline__ void evolve(float (&v0r)[NS], float (&v0i)[NS],
                                       float (&v1r)[NS], float (&v1i)[NS],
                                       const float (&gc)[56], int lane) {
#define GAPPLY(gi)                                                        \
    {                                                                     \
        float ur = gc[(gi)*4 + 0], ui = gc[(gi)*4 + 1];                   \
        float vr = gc[(gi)*4 + 2], vi = gc[(gi)*4 + 3];                   \
        _Pragma("unroll") for (int s = 0; s < NS; ++s) {                  \
            float n0r = ur * v0r[s] - ui * v0i[s] - vr * v1r[s] - vi * v1i[s]; \
            float n0i = ur * v0i[s] + ui * v0r[s] + vi * v1r[s] - vr * v1i[s]; \
            float n1r = vr * v0r[s] - vi * v0i[s] + ur * v1r[s] + ui * v1i[s]; \
            float n1i = vr * v0i[s] + vi * v0r[s] + ur * v1i[s] - ui * v1r[s]; \
            v0r[s] = n0r; v0i[s] = n0i; v1r[s] = n1r; v1i[s] = n1i;       \
        }                                                                 \
    }
#define RP32()                                                            \
    {                                                                     \
        _Pragma("unroll") for (int s = 0; s < NS; ++s) {                  \
            asm("v_permlane32_swap_b32 %0, %1" : "+v"(v0r[s]), "+v"(v1r[s])); \
            asm("v_permlane32_swap_b32 %0, %1" : "+v"(v0i[s]), "+v"(v1i[s])); \
        }                                                                 \
    }
#define RP16()                                                            \
    {                                                                     \
        _Pragma("unroll") for (int s = 0; s < NS; ++s) {                  \
            asm("v_permlane16_swap_b32 %0, %1" : "+v"(v0r[s]), "+v"(v1r[s])); \
            asm("v_permlane16_swap_b32 %0, %1" : "+v"(v0i[s]), "+v"(v1i[s])); \
        }                                                                 \
    }
#define RPB(m)                                                            \
    {                                                                     \
        bool hi = (lane & (m)) != 0;                                      \
        int ad = (lane ^ (m)) << 2;                                       \
        _Pragma("unroll") for (int s = 0; s < NS; ++s) {                  \
            float sr = hi ? v0r[s] : v1r[s];                              \
            float si = hi ? v0i[s] : v1i[s];                              \
            float rr = bperm(ad, sr);                                     \
            float ri = bperm(ad, si);                                     \
            v0r[s] = hi ? rr : v0r[s];                                    \
            v0i[s] = hi ? ri : v0i[s];                                    \
            v1r[s] = hi ? v1r[s] : rr;                                    \
            v1i[s] = hi ? v1i[s] : ri;                                    \
        }                                                                 \
    }
#define RPD(m, CTRL)                                                      \
    {                                                                     \
        bool hi = (lane & (m)) != 0;                                      \
        _Pragma("unroll") for (int s = 0; s < NS; ++s) {                  \
            float t0r = fdpp<CTRL>(v0r[s]), t0i = fdpp<CTRL>(v0i[s]);     \
            float t1r = fdpp<CTRL>(v1r[s]), t1i = fdpp<CTRL>(v1i[s]);     \
            v0r[s] = hi ? t1r : v0r[s];                                   \
            v0i[s] = hi ? t1i : v0i[s];                                   \
            v1r[s] = hi ? v1r[s] : t0r;                                   \
            v1i[s] = hi ? v1i[s] : t0i;                                   \
        }                                                                 \
    }
    {
        float ur = gc[0], ui = gc[1], vr = gc[2], vi = gc[3];
#pragma unroll
        for (int s = 0; s < NS; ++s) {
            float xx = v0r[s];
            v0r[s] = ur * xx; v0i[s] = ui * xx;
            v1r[s] = vr * xx; v1i[s] = vi * xx;
        }
    }
    RP32();
    {
        float ur = gc[4], ui = gc[5], vr = gc[6], vi = gc[7];
#pragma unroll
        for (int s = 0; s < NS; ++s) {
            float x0r = v0r[s], x0i = v0i[s];
            v0r[s] = ur * x0r - ui * x0i; v0i[s] = ur * x0i + ui * x0r;
            v1r[s] = vr * x0r - vi * x0i; v1i[s] = vr * x0i + vi * x0r;
        }
    }
    RP16();       GAPPLY(2);
    RPB(8);       GAPPLY(3);
    RPB(4);       GAPPLY(4);
    RPD(2, 0x4E); GAPPLY(5);
    RPD(1, 0xB1); GAPPLY(6);

    int kc = __popc(lane);
    float s0 = ((kc >> 1) & 1) ? -1.f : 1.f;
    float s1 = (((kc + 1) >> 1) & 1) ? -1.f : 1.f;
#pragma unroll
    for (int s = 0; s < NS; ++s) {
        v0r[s] *= s0; v0i[s] *= s0; v1r[s] *= s1; v1i[s] *= s1;
    }

    RP32();       GAPPLY(7);
    RP16();       GAPPLY(8);
    RPB(8);       GAPPLY(9);
    RPB(4);       GAPPLY(10);
    RPD(2, 0x4E); GAPPLY(11);
    RPD(1, 0xB1); GAPPLY(12);
    RP32();       GAPPLY(13);
#pragma unroll
    for (int s = 0; s < NS; ++s) {
        v0r[s] *= s0; v0i[s] *= s0; v1r[s] *= s1; v1i[s] *= s1;
    }
#undef GAPPLY
#undef RP32
#undef RP16
#undef RPB
#undef RPD
}

__device__ __forceinline__ void measure(float (&v0r)[NS], float (&v0i)[NS],
                                        float (&v1r)[NS], float (&v1i)[NS],
                                        int lane, float (&e)[NS]) {
#pragma unroll
    for (int s = 0; s < NS; ++s) {
        float t = v0r[s] * v0r[s] + v0i[s] * v0i[s] + v1r[s] * v1r[s] + v1i[s] * v1i[s];
        e[s] = (lane & 16) ? -t : t;
        e[s] = dpp_reduce(e[s]);
    }
}

// pair offset: off(k) = 31k - k(k-1)/2 (row k holds l=k+1..31)
__device__ __forceinline__ int pair_off(int k) { return 31 * k - (k * (k - 1)) / 2; }

// ---------------- kernel 1: basis evolutions -> f values --------------------
// fbuf layout per oc (stride 544): [0..31] singles f_k ; [32+off(k)+l-k-1] pairs.
__global__ __launch_bounds__(512) void prep_k(const float* __restrict__ thetas,
                                              float* __restrict__ fbuf) {
    int lane = threadIdx.x & 63;
    int iw = threadIdx.x >> 6;
    int oc = __builtin_amdgcn_readfirstlane(blockIdx.x / 17);
    int chunk = blockIdx.x % 17;

    float gc[56];
    make_gates(thetas, oc, lane, gc);

    float v0r[NS], v0i[NS], v1r[NS], v1i[NS];
    int idxs[NS];
#pragma unroll
    for (int s = 0; s < NS; ++s) {
        int idx = chunk * 32 + iw * 4 + s;
        if (idx > 527) idx = 527;
        idxs[s] = idx;
        int k, l;
        if (idx < 32) {
            k = idx; l = idx;
        } else {
            int p = idx - 32;
            k = (int)((63.0f - sqrtf(3969.0f - 8.0f * (float)p)) * 0.5f);
            if (k > 0 && pair_off(k) > p) --k;
            if (pair_off(k + 1) <= p) ++k;
            l = k + 1 + (p - pair_off(k));
        }
        v0r[s] = (lane == k || lane == l) ? 1.f : 0.f;
        v0i[s] = 0.f; v1r[s] = 0.f; v1i[s] = 0.f;
    }

    evolve(v0r, v0i, v1r, v1i, gc, lane);
    float e[NS];
    measure(v0r, v0i, v1r, v1i, lane, e);
    if (lane == 63) {
#pragma unroll
        for (int s = 0; s < NS; ++s) fbuf[oc * 544 + idxs[s]] = e[s];
    }
}

// per-k contribution: w_k * [ sum_{l>k} f_kl w_l + f_k (2 w_k - S) ]
// K compile-time -> all F offsets are s_load immediates.
template <int K>
__device__ __forceinline__ void kterm(const float* __restrict__ fo,
                                      const float (&w)[32], float S,
                                      float& a0, float& a1) {
    const float* fr = fo + 32 + (31 * K - (K * (K - 1)) / 2) - K - 1;
    float t0 = 0.f, t1 = 0.f;
#pragma unroll
    for (int j = K + 1; j < 32; j += 2) t0 = fmaf(fr[j], w[j], t0);
#pragma unroll
    for (int j = K + 2; j < 32; j += 2) t1 = fmaf(fr[j], w[j], t1);
    float t = fmaf(fo[K], fmaf(2.f, w[K], -S), t0 + t1);
    if (K & 1) a1 = fmaf(w[K], t, a1);
    else       a0 = fmaf(w[K], t, a0);
}

// ---------------- kernel 2: quadratic form, split-k wave pairs --------------
// 16 waves/block: wid&7 = oc, wid>>3 = half. Both halves: same 64 rows.
// half 0: k in {0..7, 24..31} (248 pair terms); half 1: k in {8..23} (248).
__global__ __launch_bounds__(1024, 8) void quad_k(const float* __restrict__ x,
                                                  const float* __restrict__ F,
                                                  float* __restrict__ out) {
    int lane = threadIdx.x & 63;
    int wid = threadIdx.x >> 6;
    int oc = __builtin_amdgcn_readfirstlane(wid & 7);
    int half = __builtin_amdgcn_readfirstlane(wid >> 3);

    int row = blockIdx.x * 64 + lane;
    bool valid = row < N_ROWS;
    int rc = valid ? row : (N_ROWS - 1);
    int b = rc / L_OUT;
    int l = rc - b * L_OUT;

    const float* xb = x + (b * 4) * 2048 + l;
    float w[32];
#pragma unroll
    for (int c = 0; c < 4; ++c)
#pragma unroll
        for (int k = 0; k < 8; ++k) w[c * 8 + k] = xb[c * 2048 + k];

    float n2 = 0.f, S = 0.f;
#pragma unroll
    for (int i = 0; i < 32; ++i) {
        n2 = fmaf(w[i], w[i], n2);
        S += w[i];
    }

    const float* fo = F + oc * 544;  // wave-uniform -> scalar loads
    float a0 = 0.f, a1 = 0.f;
    __shared__ float part[8][64];

    if (half) {
        kterm<8>(fo, w, S, a0, a1);  kterm<9>(fo, w, S, a0, a1);
        kterm<10>(fo, w, S, a0, a1); kterm<11>(fo, w, S, a0, a1);
        kterm<12>(fo, w, S, a0, a1); kterm<13>(fo, w, S, a0, a1);
        kterm<14>(fo, w, S, a0, a1); kterm<15>(fo, w, S, a0, a1);
        kterm<16>(fo, w, S, a0, a1); kterm<17>(fo, w, S, a0, a1);
        kterm<18>(fo, w, S, a0, a1); kterm<19>(fo, w, S, a0, a1);
        kterm<20>(fo, w, S, a0, a1); kterm<21>(fo, w, S, a0, a1);
        kterm<22>(fo, w, S, a0, a1); kterm<23>(fo, w, S, a0, a1);
        part[oc][lane] = a0 + a1;
    } else {
        kterm<0>(fo, w, S, a0, a1);  kterm<1>(fo, w, S, a0, a1);
        kterm<2>(fo, w, S, a0, a1);  kterm<3>(fo, w, S, a0, a1);
        kterm<4>(fo, w, S, a0, a1);  kterm<5>(fo, w, S, a0, a1);
        kterm<6>(fo, w, S, a0, a1);  kterm<7>(fo, w, S, a0, a1);
        kterm<24>(fo, w, S, a0, a1); kterm<25>(fo, w, S, a0, a1);
        kterm<26>(fo, w, S, a0, a1); kterm<27>(fo, w, S, a0, a1);
        kterm<28>(fo, w, S, a0, a1); kterm<29>(fo, w, S, a0, a1);
        kterm<30>(fo, w, S, a0, a1); kterm<31>(fo, w, S, a0, a1);
    }
    __syncthreads();
    if (!half && valid) {
        float tot = a0 + a1 + part[oc][lane];
        out[(b * 8 + oc) * L_OUT + l] = tot * __builtin_amdgcn_rcpf(n2);
    }
}

// ---------------- fallback: direct evolution (R4-style) ---------------------
__global__ __launch_bounds__(512) void direct_k(const float* __restrict__ x,
                                                const float* __restrict__ thetas,
                                                float* __restrict__ out) {
    int lane = threadIdx.x & 63;
    int oc = __builtin_amdgcn_readfirstlane((int)(threadIdx.x >> 6));
    float gc[56];
    make_gates(thetas, oc, lane, gc);

    int row0 = blockIdx.x * NS;
    int bidx[NS], lidx[NS];
    float v0r[NS], v0i[NS], v1r[NS], v1i[NS], acc[NS];
#pragma unroll
    for (int s = 0; s < NS; ++s) {
        int row = row0 + s;
        int b = row / L_OUT;
        bidx[s] = b;
        lidx[s] = row - b * L_OUT;
        float t = 0.f;
        if (lane < 32) {
            int c = lane >> 3, k = lane & 7;
            t = x[(b * 4 + c) * 2048 + lidx[s] + k];
        }
        acc[s] = t * t;
        v0r[s] = t; v0i[s] = 0.f; v1r[s] = 0.f; v1i[s] = 0.f;
    }
    evolve(v0r, v0i, v1r, v1i, gc, lane);
    float e[NS];
    measure(v0r, v0i, v1r, v1i, lane, e);
#pragma unroll
    for (int s = 0; s < NS; ++s) acc[s] = dpp_reduce(acc[s]);
    if (lane == 63) {
#pragma unroll
        for (int s = 0; s < NS; ++s)
            out[(bidx[s] * 8 + oc) * L_OUT + lidx[s]] =
                e[s] * __builtin_amdgcn_rcpf(acc[s]);
    }
}

extern "C" void kernel_launch(void* const* d_in, const int* in_sizes, int n_in,
                              void* d_out, int out_size, void* d_ws, size_t ws_size,
                              hipStream_t stream) {
    const float* x = (const float*)d_in[0];
    const float* thetas = (const float*)d_in[1];
    float* out = (float*)d_out;

    if (ws_size >= (8 * 544) * sizeof(float)) {
        float* fbuf = (float*)d_ws;
        prep_k<<<136, 512, 0, stream>>>(thetas, fbuf);
        quad_k<<<(N_ROWS + 63) / 64, 1024, 0, stream>>>(x, fbuf, out);
    } else {
        direct_k<<<N_ROWS / NS, 512, 0, stream>>>(x, thetas, out);
    }
}